// Round 18
// baseline (209.750 us; speedup 1.0000x reference)
//
#include <hip/hip_runtime.h>
#include <hip/hip_bf16.h>
#include <cstdint>

// ---------------------------------------------------------------------------
// MHA forward, MI355X/gfx950.  Round 18 = R16 attn with SINGLE-buffered K/V.
// R17 (KVBLK=32) regressed: per-barrier work halved, overhead won.  This
// round keeps R16's KVBLK=64 tiles (same per-iter MFMA) but drops the double
// buffer: 33KB LDS -> 4 blocks/CU = 8 waves/SIMD (launch_bounds(512,8),
// R16 VGPR=60 fits the 64 cap).  Exposed per-block stage latency is hidden
// by cross-block TLP (the R5/R16-verified mechanism).  2 barriers/iter.
// qkv (LDS-staged tiled epilogue) / out_proj / prep verbatim from R16.
// ---------------------------------------------------------------------------

using short8 = __attribute__((ext_vector_type(8))) short;
using f32x4  = __attribute__((ext_vector_type(4))) float;
using f32x16 = __attribute__((ext_vector_type(16))) float;

#define DEVINL __device__ __forceinline__

constexpr int BB  = 4;
constexpr int SS  = 2048;
constexpr int DM  = 512;
constexpr int NH  = 8;
constexpr int DKH = 64;
constexpr float C2 = 0.18033688011112042f;   // 0.125 * log2(e)

DEVINL unsigned short f2bf(float f) {
    __hip_bfloat16 h = __float2bfloat16(f);
    return *reinterpret_cast<unsigned short*>(&h);
}

DEVINL f32x4 mfma16(short8 a, short8 b, f32x4 c) {
    return __builtin_amdgcn_mfma_f32_16x16x32_bf16(a, b, c, 0, 0, 0);
}
DEVINL f32x16 mfma32(short8 a, short8 b, f32x16 c) {
    return __builtin_amdgcn_mfma_f32_32x32x16_bf16(a, b, c, 0, 0, 0);
}

DEVINL void gl16(const void* g, void* l) {
    __builtin_amdgcn_global_load_lds(
        (const __attribute__((address_space(1))) unsigned int*)g,
        (__attribute__((address_space(3))) unsigned int*)l, 16, 0, 0);
}
DEVINL void vmcnt0() { asm volatile("s_waitcnt vmcnt(0)" ::: "memory"); }

DEVINL unsigned cvtpk(float a, float b) {
    unsigned r;
    asm("v_cvt_pk_bf16_f32 %0, %1, %2" : "=v"(r) : "v"(a), "v"(b));
    return r;
}

// ---------------------------------------------------------------------------
// Kernel 0: weight prep. Wt[z][n][k] = bf16(W[z][k][n]); z = q,k,v,o.
// ---------------------------------------------------------------------------
__global__ __launch_bounds__(256)
void prep_w(const float* __restrict__ Wq, const float* __restrict__ Wk,
            const float* __restrict__ Wv, const float* __restrict__ Wo,
            unsigned short* __restrict__ wt)
{
    const int z = blockIdx.z;
    const float* W = (z == 0) ? Wq : (z == 1) ? Wk : (z == 2) ? Wv : Wo;
    unsigned short* Wtz = wt + (size_t)z * DM * DM;

    __shared__ unsigned short T[64][72];
    const int t = threadIdx.x;
    const int k0 = blockIdx.x * 64, n0 = blockIdx.y * 64;
    const int r = t >> 2, cs = t & 3;

    #pragma unroll
    for (int q = 0; q < 4; ++q) {
        float4 v = *reinterpret_cast<const float4*>(
            &W[(size_t)(k0 + r) * DM + n0 + cs * 16 + q * 4]);
        union { unsigned short u[4]; unsigned long long ll; } pk;
        pk.u[0] = f2bf(v.x); pk.u[1] = f2bf(v.y);
        pk.u[2] = f2bf(v.z); pk.u[3] = f2bf(v.w);
        *reinterpret_cast<unsigned long long*>(&T[r][cs * 16 + q * 4]) = pk.ll;
    }
    __syncthreads();
    union { unsigned short u[8]; short8 v; } p0, p1;
    #pragma unroll
    for (int e = 0; e < 8; ++e) p0.u[e] = T[cs * 16 + e][r];
    #pragma unroll
    for (int e = 0; e < 8; ++e) p1.u[e] = T[cs * 16 + 8 + e][r];
    *reinterpret_cast<short8*>(&Wtz[(size_t)(n0 + r) * DM + k0 + cs * 16]) = p0.v;
    *reinterpret_cast<short8*>(&Wtz[(size_t)(n0 + r) * DM + k0 + cs * 16 + 8]) = p1.v;
}

// ---------------------------------------------------------------------------
// Kernel 1: fused QKV projection.  128x128 tile, BK=32, 2-phase dbuf, 32KB
// LDS (one SMEM array: As = [0,8192), Bs = [8192,16384) elems).
// Epilogues:
//   z==0 -> qb row-major [bh][s][dk] (scalar stores, pre-scaled by C2)
//   z==1 -> kb2 tiled [bh][s/64][dk/8][s%64][dk%8]  via LDS-staged memcpy
//   z==2 -> vt2 tiled [bh][s/8][dk][s%8]            via LDS-staged memcpy
// ---------------------------------------------------------------------------
__global__ __launch_bounds__(256, 4)
void qkv_proj_kernel(const float* __restrict__ Qin, const float* __restrict__ Kin,
                     const float* __restrict__ Vin,
                     const unsigned short* __restrict__ wt,
                     const float* __restrict__ bq, const float* __restrict__ bk,
                     const float* __restrict__ bv,
                     unsigned short* __restrict__ qb, unsigned short* __restrict__ kb2,
                     unsigned short* __restrict__ vt2)
{
    const int z = blockIdx.z;
    const float* A           = (z == 0) ? Qin : (z == 1) ? Kin : Vin;
    const unsigned short* Wt = wt + (size_t)z * DM * DM;
    const float* bias        = (z == 0) ? bq : (z == 1) ? bk : bv;

    __shared__ unsigned short SMEM[16384];   // 32 KB

    const int tid = threadIdx.x, lane = tid & 63, w = tid >> 6;
    const int wm = w >> 1, wn = w & 1;
    const int row16 = lane & 15, kg = lane >> 4;
    const int m0tok = blockIdx.x * 128, n0ch = blockIdx.y * 128;

    const int ar = tid >> 1, ah = tid & 1;

    float4 apf[4];
    auto load_A = [&](int kt) {
        const float* Ap = &A[(size_t)(m0tok + ar) * DM + kt * 32 + ah * 16];
        #pragma unroll
        for (int q = 0; q < 4; ++q)
            apf[q] = *reinterpret_cast<const float4*>(Ap + q * 4);
    };
    auto write_A = [&](int buf) {
        #pragma unroll
        for (int s = 0; s < 2; ++s) {
            union { unsigned short u[8]; short8 v; } pk;
            float4 a = apf[2 * s], b = apf[2 * s + 1];
            pk.u[0] = f2bf(a.x); pk.u[1] = f2bf(a.y);
            pk.u[2] = f2bf(a.z); pk.u[3] = f2bf(a.w);
            pk.u[4] = f2bf(b.x); pk.u[5] = f2bf(b.y);
            pk.u[6] = f2bf(b.z); pk.u[7] = f2bf(b.w);
            int phys = (ah * 2 + s) ^ (ar & 3);
            *reinterpret_cast<short8*>(&SMEM[buf * 4096 + ar * 32 + phys * 8]) = pk.v;
        }
    };
    auto issue_B = [&](int kt, int buf) {
        #pragma unroll
        for (int i = 0; i < 2; ++i) {
            int chunk = tid + i * 256;
            int n = chunk >> 2, c = chunk & 3;
            const unsigned short* src =
                &Wt[(size_t)(n0ch + n) * DM + kt * 32 + ((c ^ (n & 3)) * 8)];
            gl16(src, (char*)SMEM + 16384 + (size_t)buf * 8192 +
                      (size_t)(w * 64 + i * 256) * 16);
        }
    };

    f32x4 acc[4][4] = {};
    const int aoff = ((z == 2) ? wn : wm) * 64;
    const int boff = ((z == 2) ? wm : wn) * 64;

    load_A(0); issue_B(0, 0);
    vmcnt0();
    write_A(0);
    __syncthreads();

    for (int t = 0; t < 16; ++t) {
        const int cur = t & 1, nxt = cur ^ 1;
        if (t + 1 < 16) { issue_B(t + 1, nxt); load_A(t + 1); }

        short8 af[4], bfr[4];
        #pragma unroll
        for (int i = 0; i < 4; ++i) {
            int ra = aoff + i * 16 + row16;
            int rb = boff + i * 16 + row16;
            af[i]  = *reinterpret_cast<const short8*>(
                &SMEM[cur * 4096 + ra * 32 + ((kg ^ (ra & 3)) * 8)]);
            bfr[i] = *reinterpret_cast<const short8*>(
                &SMEM[8192 + cur * 4096 + rb * 32 + ((kg ^ (rb & 3)) * 8)]);
        }
        __builtin_amdgcn_s_setprio(1);
        #pragma unroll
        for (int mf = 0; mf < 4; ++mf)
            #pragma unroll
            for (int nf = 0; nf < 4; ++nf)
                acc[mf][nf] = (z == 2)
                    ? mfma16(bfr[mf], af[nf], acc[mf][nf])
                    : mfma16(af[mf], bfr[nf], acc[mf][nf]);
        __builtin_amdgcn_s_setprio(0);

        vmcnt0();
        if (t + 1 < 16) write_A(nxt);
        __syncthreads();
    }

    if (z == 0) {
        #pragma unroll
        for (int nf = 0; nf < 4; ++nf) {
            int ch = n0ch + wn * 64 + nf * 16 + row16;
            float bval = bias[ch];
            int h = ch >> 6, dk = ch & 63;
            #pragma unroll
            for (int mf = 0; mf < 4; ++mf)
                #pragma unroll
                for (int j = 0; j < 4; ++j) {
                    int tok = m0tok + wm * 64 + mf * 16 + kg * 4 + j;
                    int b = tok >> 11, s = tok & 2047;
                    qb[(((size_t)b * NH + h) * SS + s) * DKH + dk] =
                        f2bf((acc[mf][nf][j] + bval) * C2);
                }
        }
    } else {
        // ---- LDS-staged coalesced tile epilogue (kb2 / vt2) ----
        __syncthreads();
        if (z == 1) {
            #pragma unroll
            for (int nf = 0; nf < 4; ++nf) {
                int dk = nf * 16 + row16;
                float bval = bias[n0ch + wn * 64 + dk];
                #pragma unroll
                for (int mf = 0; mf < 4; ++mf)
                    #pragma unroll
                    for (int j = 0; j < 4; ++j) {
                        int s6 = mf * 16 + kg * 4 + j;
                        SMEM[w * 4096 + (dk >> 3) * 512 + s6 * 8 + (dk & 7)] =
                            f2bf(acc[mf][nf][j] + bval);
                    }
            }
        } else {
            const int tile = wn * 2 + wm;
            #pragma unroll
            for (int mf = 0; mf < 4; ++mf)
                #pragma unroll
                for (int j = 0; j < 4; ++j) {
                    int dk6 = mf * 16 + kg * 4 + j;
                    float bval = bias[n0ch + wm * 64 + dk6];
                    #pragma unroll
                    for (int nf = 0; nf < 4; ++nf) {
                        int s6 = nf * 16 + row16;
                        SMEM[tile * 4096 + (s6 >> 3) * 512 + dk6 * 8 + (s6 & 7)] =
                            f2bf(acc[mf][nf][j] + bval);
                    }
                }
        }
        __syncthreads();
        const int sblk = m0tok + (w >> 1) * 64;
        const int hg   = (n0ch >> 6) + (w & 1);
        const int b    = sblk >> 11, s_in_b = sblk & 2047;
        unsigned short* dst =
            ((z == 1) ? kb2 : vt2) +
            ((size_t)(b * NH + hg)) * (SS * DKH) + (size_t)(s_in_b >> 6) * 4096;
        #pragma unroll
        for (int i = 0; i < 8; ++i)
            *reinterpret_cast<short8*>(&dst[i * 512 + lane * 8]) =
                *reinterpret_cast<const short8*>(&SMEM[w * 4096 + i * 512 + lane * 8]);
    }
}

// ---------------------------------------------------------------------------
// Kernel 2: flash attention, KV-split + SINGLE-buffered KVBLK=64 tiles.
// 512 threads = 4 q-waves x 2 kv-halves; each wave 32 q x 1024 kv (16 tiles).
// Per half: K[1]+V[1] 8KB buffers -> 33KB LDS -> 4 blocks/CU = 8 waves/SIMD.
// 2 barriers/iter (compute-done, stage-done); cross-block TLP hides the
// exposed stage latency.  Fixed-max softmax (exp2-units, Q pre-scaled),
// in-register P via cvt_pk+permlane32_swap.  Combine O=(oL+oR)/(lL+lR).
// ---------------------------------------------------------------------------
__global__ __launch_bounds__(512, 8)
void attn_kernel(const unsigned short* __restrict__ qb,
                 const unsigned short* __restrict__ kb2,
                 const unsigned short* __restrict__ vt2,
                 unsigned short* __restrict__ am)
{
    // [0,8192):     K = [hf][c(8)][kv(64)][8]   (4096 elems per half)
    // [8192,16384): V = [hf][kvc(8)][dk(64)][8]
    // [16384,16896): lcomb scratch
    __shared__ unsigned short SMEM[16896];   // 33 KB

    const int tid = threadIdx.x, lane = tid & 63, w = tid >> 6;
    const int wq = w & 3, hf = w >> 2;          // q-wave id, kv-half id
    const int l31 = lane & 31, hi = lane >> 5;
    const int bh = blockIdx.y, b = bh >> 3, h = bh & 7;
    const int q0 = blockIdx.x * 128;
    const size_t base = (size_t)bh * (SS * DKH);

    unsigned short* Kb = SMEM + hf * 4096;
    unsigned short* Vb = SMEM + 8192 + hf * 4096;

    // stage tile tl (0..15) of this half: K 512 + V 512 chunks over 4 waves
    // -> 2 gl16 K + 2 gl16 V per thread.
    auto stage_KV = [&](int tl) {
        const int tt = hf * 16 + tl;
        const unsigned short* ksrc = kb2 + base + (size_t)tt * 4096;
        const unsigned short* vsrc = vt2 + base + (size_t)tt * 4096;
        #pragma unroll
        for (int i = 0; i < 2; ++i) {
            int cb = i * 256 + wq * 64;          // wave-uniform chunk base
            gl16(ksrc + (size_t)(cb + lane) * 8, (char*)Kb + (size_t)cb * 16);
            gl16(vsrc + (size_t)(cb + lane) * 8, (char*)Vb + (size_t)cb * 16);
        }
    };

    // ---- Q fragments direct to registers (B-operand: col=q, k=d) ----
    short8 qf[4];
    const int qrow = q0 + wq * 32 + l31;
    #pragma unroll
    for (int ks = 0; ks < 4; ++ks)
        qf[ks] = *reinterpret_cast<const short8*>(
            &qb[base + (size_t)qrow * DKH + (ks * 2 + hi) * 8]);
    vmcnt0();

    stage_KV(0);
    __syncthreads();               // tile 0 of both halves resident

    f32x16 o[2] = {};
    float lsum = 0.f;
    unsigned pk[2][4][2];

    auto do_QK = [&](f32x16 (&sfr)[2]) {
        #pragma unroll
        for (int ks = 0; ks < 4; ++ks) {
            int c = ks * 2 + hi;
            #pragma unroll
            for (int mkv = 0; mkv < 2; ++mkv) {
                short8 kf = *reinterpret_cast<const short8*>(
                    &Kb[(c * 64 + mkv * 32 + l31) * 8]);
                sfr[mkv] = mfma32(kf, qf[ks], sfr[mkv]);
            }
        }
    };
    auto do_softmax = [&](const f32x16 (&sfr)[2]) {
        #pragma unroll
        for (int mkv = 0; mkv < 2; ++mkv)
            #pragma unroll
            for (int bq = 0; bq < 4; ++bq) {
                float p0 = __builtin_amdgcn_exp2f(sfr[mkv][bq * 4 + 0]);
                float p1 = __builtin_amdgcn_exp2f(sfr[mkv][bq * 4 + 1]);
                float p2 = __builtin_amdgcn_exp2f(sfr[mkv][bq * 4 + 2]);
                float p3 = __builtin_amdgcn_exp2f(sfr[mkv][bq * 4 + 3]);
                lsum += (p0 + p1) + (p2 + p3);
                pk[mkv][bq][0] = cvtpk(p0, p1);
                pk[mkv][bq][1] = cvtpk(p2, p3);
            }
    };
    auto do_PV = [&]() {
        #pragma unroll
        for (int ks2 = 0; ks2 < 4; ++ks2) {
            const int mkv = ks2 >> 1, b0 = (ks2 & 1) * 2, b1 = b0 + 1;
            unsigned x0 = pk[mkv][b0][0], y0 = pk[mkv][b1][0];
            unsigned x1 = pk[mkv][b0][1], y1 = pk[mkv][b1][1];
            asm volatile("v_permlane32_swap_b32 %0, %1" : "+v"(x0), "+v"(y0));
            asm volatile("v_permlane32_swap_b32 %0, %1" : "+v"(x1), "+v"(y1));
            union { unsigned u[4]; short8 s; } pa;
            pa.u[0] = x0; pa.u[1] = x1; pa.u[2] = y0; pa.u[3] = y1;
            int c = ks2 * 2 + hi;
            #pragma unroll
            for (int ndk = 0; ndk < 2; ++ndk) {
                short8 vf = *reinterpret_cast<const short8*>(
                    &Vb[(c * 64 + ndk * 32 + l31) * 8]);
                o[ndk] = mfma32(pa.s, vf, o[ndk]);
            }
        }
    };

    // ---- main loop: 16 tiles per half, single buffer, 2 barriers/iter ----
    for (int tl = 0; tl < 16; ++tl) {
        f32x16 sfr[2] = {};
        __builtin_amdgcn_s_setprio(1);
        do_QK(sfr);
        __builtin_amdgcn_s_setprio(0);
        do_softmax(sfr);
        __builtin_amdgcn_s_setprio(1);
        do_PV();
        __builtin_amdgcn_s_setprio(0);

        if (tl < 15) {
            __syncthreads();       // everyone done reading tile tl
            stage_KV(tl + 1);
            __syncthreads();       // tile tl+1 resident (drains staging)
        }
    }

    // ---- combine halves through LDS: O=(oL+oR)/(lL+lR) ----
    __syncthreads();
    float* comb  = reinterpret_cast<float*>(SMEM);           // 8192 floats
    float* lcomb = reinterpret_cast<float*>(SMEM + 16384);   // 256 floats
    if (hf == 1) {
        #pragma unroll
        for (int ndk = 0; ndk < 2; ++ndk)
            #pragma unroll
            for (int r = 0; r < 16; ++r)
                comb[((wq * 2 + ndk) * 16 + r) * 64 + lane] = o[ndk][r];
        lcomb[wq * 64 + lane] = lsum;
    }
    __syncthreads();
    if (hf == 0) {
        lsum += lcomb[wq * 64 + lane];
        float lfull = lsum + __shfl_xor(lsum, 32, 64);
        float linv = 1.0f / lfull;
        #pragma unroll
        for (int ndk = 0; ndk < 2; ++ndk)
            #pragma unroll
            for (int r = 0; r < 16; ++r)
                o[ndk][r] += comb[((wq * 2 + ndk) * 16 + r) * 64 + lane];
        #pragma unroll
        for (int r = 0; r < 16; ++r) {
            int qloc = (r & 3) + 8 * (r >> 2) + 4 * hi;
            float li = __shfl(linv, qloc, 64);
            int sg = q0 + wq * 32 + qloc;
            #pragma unroll
            for (int ndk = 0; ndk < 2; ++ndk) {
                int dk = ndk * 32 + l31;
                am[((size_t)b * SS + sg) * DM + h * DKH + dk] =
                    f2bf(o[ndk][r] * li);
            }
        }
    }
}

// ---------------------------------------------------------------------------
// Kernel 3: output projection, 64x128 tile (grid 512), BK=32, 2-phase dbuf.
// ---------------------------------------------------------------------------
__global__ __launch_bounds__(256, 4)
void out_proj_kernel(const unsigned short* __restrict__ am,
                     const unsigned short* __restrict__ Wt,
                     const float* __restrict__ bo,
                     float* __restrict__ out)
{
    __shared__ unsigned short As[2][64 * 32];
    __shared__ unsigned short Bs[2][128 * 32];

    const int tid = threadIdx.x, lane = tid & 63, w = tid >> 6;
    const int wm = w & 1, wn = w >> 1;
    const int row16 = lane & 15, kg = lane >> 4;
    const int m0 = blockIdx.x * 64;
    const int n0 = blockIdx.y * 128;

    auto stage = [&](int kt, int buf) {
        {
            int r = tid >> 2, c = tid & 3;
            gl16(&am[(size_t)(m0 + r) * DM + kt * 32 + ((c ^ (r & 3)) * 8)],
                 (char*)As + (size_t)buf * 4096 + (size_t)(w * 64) * 16);
        }
        #pragma unroll
        for (int i = 0; i < 2; ++i) {
            int cc = tid + i * 256;
            int n = cc >> 2, c = cc & 3;
            gl16(&Wt[(size_t)(n0 + n) * DM + kt * 32 + ((c ^ (n & 3)) * 8)],
                 (char*)Bs + (size_t)buf * 8192 + (size_t)(w * 64 + i * 256) * 16);
        }
    };

    f32x4 acc[2][4] = {};

    stage(0, 0);
    vmcnt0();
    __syncthreads();

    for (int t = 0; t < 16; ++t) {
        const int cur = t & 1, nxt = cur ^ 1;
        if (t + 1 < 16) stage(t + 1, nxt);

        short8 af[2], bfr[4];
        #pragma unroll
        for (int i = 0; i < 2; ++i) {
            int ra = wm * 32 + i * 16 + row16;
            af[i] = *reinterpret_cast<const short8*>(
                &As[cur][ra * 32 + ((kg ^ (ra & 3)) * 8)]);
        }
        #pragma unroll
        for (int i = 0; i < 4; ++i) {
            int rb = wn * 64 + i * 16 + row16;
            bfr[i] = *reinterpret_cast<const short8*>(
                &Bs[cur][rb * 32 + ((kg ^ (rb & 3)) * 8)]);
        }
        __builtin_amdgcn_s_setprio(1);
        #pragma unroll
        for (int mf = 0; mf < 2; ++mf)
            #pragma unroll
            for (int nf = 0; nf < 4; ++nf)
                acc[mf][nf] = mfma16(af[mf], bfr[nf], acc[mf][nf]);
        __builtin_amdgcn_s_setprio(0);

        vmcnt0();
        __syncthreads();
    }

    #pragma unroll
    for (int nf = 0; nf < 4; ++nf) {
        int n = n0 + wn * 64 + nf * 16 + row16;
        float bval = bo[n];
        #pragma unroll
        for (int mf = 0; mf < 2; ++mf)
            #pragma unroll
            for (int j = 0; j < 4; ++j) {
                int mrow = m0 + wm * 32 + mf * 16 + kg * 4 + j;
                out[(size_t)mrow * DM + n] = acc[mf][nf][j] + bval;
            }
    }
}

// ---------------------------------------------------------------------------
extern "C" void kernel_launch(void* const* d_in, const int* in_sizes, int n_in,
                              void* d_out, int out_size, void* d_ws, size_t ws_size,
                              hipStream_t stream) {
    const float* Q  = (const float*)d_in[0];
    const float* K  = (const float*)d_in[1];
    const float* V  = (const float*)d_in[2];
    const float* Wq = (const float*)d_in[3];
    const float* bq = (const float*)d_in[4];
    const float* Wk = (const float*)d_in[5];
    const float* bk = (const float*)d_in[6];
    const float* Wv = (const float*)d_in[7];
    const float* bv = (const float*)d_in[8];
    const float* Wo = (const float*)d_in[9];
    const float* bo = (const float*)d_in[10];
    float* out = (float*)d_out;

    const size_t per = (size_t)BB * NH * SS * DKH;   // 4,194,304 bf16 elems
    unsigned short* qb  = (unsigned short*)d_ws;     // [bh][s][dk]
    unsigned short* kb2 = qb + per;                  // tiled K
    unsigned short* vt2 = kb2 + per;                 // tiled V^T
    unsigned short* am  = vt2 + per;
    unsigned short* wt  = am + per;                  // 4 x 512x512 bf16

    prep_w<<<dim3(8, 8, 4), 256, 0, stream>>>(Wq, Wk, Wv, Wo, wt);
    qkv_proj_kernel<<<dim3(64, 4, 3), 256, 0, stream>>>(
        Q, K, V, wt, bq, bk, bv, qb, kb2, vt2);
    attn_kernel<<<dim3(SS / 128, BB * NH), 512, 0, stream>>>(qb, kb2, vt2, am);
    out_proj_kernel<<<dim3(128, 4), 256, 0, stream>>>(
        am, wt + 3 * (size_t)DM * DM, bo, out);
}

// Round 19
// 87.421 us; speedup vs baseline: 2.3993x; 2.3993x over previous
//
#include <hip/hip_runtime.h>
#include <hip/hip_bf16.h>
#include <cstdint>

// ---------------------------------------------------------------------------
// MHA forward, MI355X/gfx950.  Round 19 = exact restore of Round 16 (best
// verified: 87.6us total, attn 49.1us).  R17 (KVBLK=32: barrier overhead) and
// R18 (launch_bounds(512,8): VGPR cap 64 -> accumulator spill, 312MB scratch
// writes) both regressed; this banks the measured optimum.
// attn: 512 threads = 4 q-waves x 2 kv-halves (KV-split -> 4 waves/SIMD),
// KVBLK=64, per-half K[2]/V[2] double-buffer, chunk-major conflict-free LDS,
// 1-ahead gl16 staging, one __syncthreads per tile, fixed-max softmax in
// exp2-units (Q pre-scaled by C2), in-register P via cvt_pk+permlane32_swap,
// combine O=(oL+oR)/(lL+lR) through the dead streaming LDS.
// qkv: 128x128/BK=32 2-phase dbuf GEMM; K/V outputs pre-tiled via LDS-staged
// coalesced epilogue.  out_proj: 64x128/BK=32 2-phase dbuf.
// ---------------------------------------------------------------------------

using short8 = __attribute__((ext_vector_type(8))) short;
using f32x4  = __attribute__((ext_vector_type(4))) float;
using f32x16 = __attribute__((ext_vector_type(16))) float;

#define DEVINL __device__ __forceinline__

constexpr int BB  = 4;
constexpr int SS  = 2048;
constexpr int DM  = 512;
constexpr int NH  = 8;
constexpr int DKH = 64;
constexpr float C2 = 0.18033688011112042f;   // 0.125 * log2(e)

DEVINL unsigned short f2bf(float f) {
    __hip_bfloat16 h = __float2bfloat16(f);
    return *reinterpret_cast<unsigned short*>(&h);
}

DEVINL f32x4 mfma16(short8 a, short8 b, f32x4 c) {
    return __builtin_amdgcn_mfma_f32_16x16x32_bf16(a, b, c, 0, 0, 0);
}
DEVINL f32x16 mfma32(short8 a, short8 b, f32x16 c) {
    return __builtin_amdgcn_mfma_f32_32x32x16_bf16(a, b, c, 0, 0, 0);
}

DEVINL void gl16(const void* g, void* l) {
    __builtin_amdgcn_global_load_lds(
        (const __attribute__((address_space(1))) unsigned int*)g,
        (__attribute__((address_space(3))) unsigned int*)l, 16, 0, 0);
}
DEVINL void vmcnt0() { asm volatile("s_waitcnt vmcnt(0)" ::: "memory"); }

DEVINL unsigned cvtpk(float a, float b) {
    unsigned r;
    asm("v_cvt_pk_bf16_f32 %0, %1, %2" : "=v"(r) : "v"(a), "v"(b));
    return r;
}

// ---------------------------------------------------------------------------
// Kernel 0: weight prep. Wt[z][n][k] = bf16(W[z][k][n]); z = q,k,v,o.
// ---------------------------------------------------------------------------
__global__ __launch_bounds__(256)
void prep_w(const float* __restrict__ Wq, const float* __restrict__ Wk,
            const float* __restrict__ Wv, const float* __restrict__ Wo,
            unsigned short* __restrict__ wt)
{
    const int z = blockIdx.z;
    const float* W = (z == 0) ? Wq : (z == 1) ? Wk : (z == 2) ? Wv : Wo;
    unsigned short* Wtz = wt + (size_t)z * DM * DM;

    __shared__ unsigned short T[64][72];
    const int t = threadIdx.x;
    const int k0 = blockIdx.x * 64, n0 = blockIdx.y * 64;
    const int r = t >> 2, cs = t & 3;

    #pragma unroll
    for (int q = 0; q < 4; ++q) {
        float4 v = *reinterpret_cast<const float4*>(
            &W[(size_t)(k0 + r) * DM + n0 + cs * 16 + q * 4]);
        union { unsigned short u[4]; unsigned long long ll; } pk;
        pk.u[0] = f2bf(v.x); pk.u[1] = f2bf(v.y);
        pk.u[2] = f2bf(v.z); pk.u[3] = f2bf(v.w);
        *reinterpret_cast<unsigned long long*>(&T[r][cs * 16 + q * 4]) = pk.ll;
    }
    __syncthreads();
    union { unsigned short u[8]; short8 v; } p0, p1;
    #pragma unroll
    for (int e = 0; e < 8; ++e) p0.u[e] = T[cs * 16 + e][r];
    #pragma unroll
    for (int e = 0; e < 8; ++e) p1.u[e] = T[cs * 16 + 8 + e][r];
    *reinterpret_cast<short8*>(&Wtz[(size_t)(n0 + r) * DM + k0 + cs * 16]) = p0.v;
    *reinterpret_cast<short8*>(&Wtz[(size_t)(n0 + r) * DM + k0 + cs * 16 + 8]) = p1.v;
}

// ---------------------------------------------------------------------------
// Kernel 1: fused QKV projection.  128x128 tile, BK=32, 2-phase dbuf, 32KB
// LDS (one SMEM array: As = [0,8192), Bs = [8192,16384) elems).
// Epilogues:
//   z==0 -> qb row-major [bh][s][dk] (scalar stores, pre-scaled by C2)
//   z==1 -> kb2 tiled [bh][s/64][dk/8][s%64][dk%8]  via LDS-staged memcpy
//   z==2 -> vt2 tiled [bh][s/8][dk][s%8]            via LDS-staged memcpy
// ---------------------------------------------------------------------------
__global__ __launch_bounds__(256, 4)
void qkv_proj_kernel(const float* __restrict__ Qin, const float* __restrict__ Kin,
                     const float* __restrict__ Vin,
                     const unsigned short* __restrict__ wt,
                     const float* __restrict__ bq, const float* __restrict__ bk,
                     const float* __restrict__ bv,
                     unsigned short* __restrict__ qb, unsigned short* __restrict__ kb2,
                     unsigned short* __restrict__ vt2)
{
    const int z = blockIdx.z;
    const float* A           = (z == 0) ? Qin : (z == 1) ? Kin : Vin;
    const unsigned short* Wt = wt + (size_t)z * DM * DM;
    const float* bias        = (z == 0) ? bq : (z == 1) ? bk : bv;

    __shared__ unsigned short SMEM[16384];   // 32 KB: As[2][128][32] | Bs[2][128][32]

    const int tid = threadIdx.x, lane = tid & 63, w = tid >> 6;
    const int wm = w >> 1, wn = w & 1;
    const int row16 = lane & 15, kg = lane >> 4;
    const int m0tok = blockIdx.x * 128, n0ch = blockIdx.y * 128;

    const int ar = tid >> 1, ah = tid & 1;

    float4 apf[4];
    auto load_A = [&](int kt) {
        const float* Ap = &A[(size_t)(m0tok + ar) * DM + kt * 32 + ah * 16];
        #pragma unroll
        for (int q = 0; q < 4; ++q)
            apf[q] = *reinterpret_cast<const float4*>(Ap + q * 4);
    };
    auto write_A = [&](int buf) {
        #pragma unroll
        for (int s = 0; s < 2; ++s) {
            union { unsigned short u[8]; short8 v; } pk;
            float4 a = apf[2 * s], b = apf[2 * s + 1];
            pk.u[0] = f2bf(a.x); pk.u[1] = f2bf(a.y);
            pk.u[2] = f2bf(a.z); pk.u[3] = f2bf(a.w);
            pk.u[4] = f2bf(b.x); pk.u[5] = f2bf(b.y);
            pk.u[6] = f2bf(b.z); pk.u[7] = f2bf(b.w);
            int phys = (ah * 2 + s) ^ (ar & 3);
            *reinterpret_cast<short8*>(&SMEM[buf * 4096 + ar * 32 + phys * 8]) = pk.v;
        }
    };
    auto issue_B = [&](int kt, int buf) {
        #pragma unroll
        for (int i = 0; i < 2; ++i) {
            int chunk = tid + i * 256;
            int n = chunk >> 2, c = chunk & 3;
            const unsigned short* src =
                &Wt[(size_t)(n0ch + n) * DM + kt * 32 + ((c ^ (n & 3)) * 8)];
            gl16(src, (char*)SMEM + 16384 + (size_t)buf * 8192 +
                      (size_t)(w * 64 + i * 256) * 16);
        }
    };

    f32x4 acc[4][4] = {};
    const int aoff = ((z == 2) ? wn : wm) * 64;
    const int boff = ((z == 2) ? wm : wn) * 64;

    load_A(0); issue_B(0, 0);
    vmcnt0();
    write_A(0);
    __syncthreads();

    for (int t = 0; t < 16; ++t) {
        const int cur = t & 1, nxt = cur ^ 1;
        if (t + 1 < 16) { issue_B(t + 1, nxt); load_A(t + 1); }

        short8 af[4], bfr[4];
        #pragma unroll
        for (int i = 0; i < 4; ++i) {
            int ra = aoff + i * 16 + row16;
            int rb = boff + i * 16 + row16;
            af[i]  = *reinterpret_cast<const short8*>(
                &SMEM[cur * 4096 + ra * 32 + ((kg ^ (ra & 3)) * 8)]);
            bfr[i] = *reinterpret_cast<const short8*>(
                &SMEM[8192 + cur * 4096 + rb * 32 + ((kg ^ (rb & 3)) * 8)]);
        }
        __builtin_amdgcn_s_setprio(1);
        #pragma unroll
        for (int mf = 0; mf < 4; ++mf)
            #pragma unroll
            for (int nf = 0; nf < 4; ++nf)
                acc[mf][nf] = (z == 2)
                    ? mfma16(bfr[mf], af[nf], acc[mf][nf])
                    : mfma16(af[mf], bfr[nf], acc[mf][nf]);
        __builtin_amdgcn_s_setprio(0);

        vmcnt0();
        if (t + 1 < 16) write_A(nxt);
        __syncthreads();
    }

    if (z == 0) {
        #pragma unroll
        for (int nf = 0; nf < 4; ++nf) {
            int ch = n0ch + wn * 64 + nf * 16 + row16;
            float bval = bias[ch];
            int h = ch >> 6, dk = ch & 63;
            #pragma unroll
            for (int mf = 0; mf < 4; ++mf)
                #pragma unroll
                for (int j = 0; j < 4; ++j) {
                    int tok = m0tok + wm * 64 + mf * 16 + kg * 4 + j;
                    int b = tok >> 11, s = tok & 2047;
                    qb[(((size_t)b * NH + h) * SS + s) * DKH + dk] =
                        f2bf((acc[mf][nf][j] + bval) * C2);
                }
        }
    } else {
        // ---- LDS-staged coalesced tile epilogue (kb2 / vt2) ----
        __syncthreads();   // all waves done reading SMEM fragments
        if (z == 1) {
            #pragma unroll
            for (int nf = 0; nf < 4; ++nf) {
                int dk = nf * 16 + row16;
                float bval = bias[n0ch + wn * 64 + dk];
                #pragma unroll
                for (int mf = 0; mf < 4; ++mf)
                    #pragma unroll
                    for (int j = 0; j < 4; ++j) {
                        int s6 = mf * 16 + kg * 4 + j;
                        SMEM[w * 4096 + (dk >> 3) * 512 + s6 * 8 + (dk & 7)] =
                            f2bf(acc[mf][nf][j] + bval);
                    }
            }
        } else {
            const int tile = wn * 2 + wm;
            #pragma unroll
            for (int mf = 0; mf < 4; ++mf)
                #pragma unroll
                for (int j = 0; j < 4; ++j) {
                    int dk6 = mf * 16 + kg * 4 + j;
                    float bval = bias[n0ch + wm * 64 + dk6];
                    #pragma unroll
                    for (int nf = 0; nf < 4; ++nf) {
                        int s6 = nf * 16 + row16;
                        SMEM[tile * 4096 + (s6 >> 3) * 512 + dk6 * 8 + (s6 & 7)] =
                            f2bf(acc[mf][nf][j] + bval);
                    }
                }
        }
        __syncthreads();
        const int sblk = m0tok + (w >> 1) * 64;
        const int hg   = (n0ch >> 6) + (w & 1);
        const int b    = sblk >> 11, s_in_b = sblk & 2047;
        unsigned short* dst =
            ((z == 1) ? kb2 : vt2) +
            ((size_t)(b * NH + hg)) * (SS * DKH) + (size_t)(s_in_b >> 6) * 4096;
        #pragma unroll
        for (int i = 0; i < 8; ++i)
            *reinterpret_cast<short8*>(&dst[i * 512 + lane * 8]) =
                *reinterpret_cast<const short8*>(&SMEM[w * 4096 + i * 512 + lane * 8]);
    }
}

// ---------------------------------------------------------------------------
// Kernel 2: flash attention, in-block KV-split.  512 threads = 4 q-waves x
// 2 kv-halves; QBLK=128, each wave 32 q x 1024 kv (16 tiles).  Per half:
// chunk-major K[2]/V[2] double-buffer, 1-ahead staging, one __syncthreads
// per tile.  Fixed-max softmax (exp2-units, Q pre-scaled), in-register P via
// cvt_pk+permlane32_swap.  Combine: O=(oL+oR)/(lL+lR) through 32KB of the
// (dead) streaming LDS.  Grid (16,32) -> 2 blocks/CU = 4 waves/SIMD.
// ---------------------------------------------------------------------------
__global__ __launch_bounds__(512, 4)
void attn_kernel(const unsigned short* __restrict__ qb,
                 const unsigned short* __restrict__ kb2,
                 const unsigned short* __restrict__ vt2,
                 unsigned short* __restrict__ am)
{
    __shared__ unsigned short Ks[2][2][4096];   // [half][buf][d-chunk][kv]
    __shared__ unsigned short Vs[2][2][4096];   // [half][buf][kv-chunk][dk]

    const int tid = threadIdx.x, lane = tid & 63, w = tid >> 6;
    const int wq = w & 3, hf = w >> 2;          // q-wave id, kv-half id
    const int l31 = lane & 31, hi = lane >> 5;
    const int bh = blockIdx.y, b = bh >> 3, h = bh & 7;
    const int q0 = blockIdx.x * 128;
    const size_t base = (size_t)bh * (SS * DKH);
    const int tile0 = hf * 16;                  // this half's first kv tile

    // stage local tile tl (0..15) into this half's buffers; each half's
    // 4 waves cover K(512 chunks)+V(512 chunks): 4 gl16 per thread.
    auto stage_KV = [&](int tl) {
        const int tt = tile0 + tl, buf = tl & 1;
        const unsigned short* ksrc = kb2 + base + (size_t)tt * 4096;
        const unsigned short* vsrc = vt2 + base + (size_t)tt * 4096;
        #pragma unroll
        for (int i = 0; i < 2; ++i) {
            int cb = i * 256 + wq * 64;          // wave-uniform chunk base
            gl16(ksrc + (size_t)(cb + lane) * 8,
                 (char*)Ks[hf][buf] + (size_t)cb * 16);
            gl16(vsrc + (size_t)(cb + lane) * 8,
                 (char*)Vs[hf][buf] + (size_t)cb * 16);
        }
    };

    // ---- Q fragments direct to registers (B-operand: col=q, k=d) ----
    short8 qf[4];
    const int qrow = q0 + wq * 32 + l31;
    #pragma unroll
    for (int ks = 0; ks < 4; ++ks)
        qf[ks] = *reinterpret_cast<const short8*>(
            &qb[base + (size_t)qrow * DKH + (ks * 2 + hi) * 8]);
    vmcnt0();

    stage_KV(0);
    __syncthreads();               // tile 0 of both halves resident

    f32x16 o[2] = {};
    float lsum = 0.f;
    unsigned pk[2][4][2];

    auto do_QK = [&](int buf, f32x16 (&sfr)[2]) {
        #pragma unroll
        for (int ks = 0; ks < 4; ++ks) {
            int c = ks * 2 + hi;
            #pragma unroll
            for (int mkv = 0; mkv < 2; ++mkv) {
                short8 kf = *reinterpret_cast<const short8*>(
                    &Ks[hf][buf][(c * 64 + mkv * 32 + l31) * 8]);
                sfr[mkv] = mfma32(kf, qf[ks], sfr[mkv]);
            }
        }
    };
    auto do_softmax = [&](const f32x16 (&sfr)[2]) {
        #pragma unroll
        for (int mkv = 0; mkv < 2; ++mkv)
            #pragma unroll
            for (int bq = 0; bq < 4; ++bq) {
                float p0 = __builtin_amdgcn_exp2f(sfr[mkv][bq * 4 + 0]);
                float p1 = __builtin_amdgcn_exp2f(sfr[mkv][bq * 4 + 1]);
                float p2 = __builtin_amdgcn_exp2f(sfr[mkv][bq * 4 + 2]);
                float p3 = __builtin_amdgcn_exp2f(sfr[mkv][bq * 4 + 3]);
                lsum += (p0 + p1) + (p2 + p3);
                pk[mkv][bq][0] = cvtpk(p0, p1);
                pk[mkv][bq][1] = cvtpk(p2, p3);
            }
    };
    auto do_PV = [&](int buf) {
        #pragma unroll
        for (int ks2 = 0; ks2 < 4; ++ks2) {
            const int mkv = ks2 >> 1, b0 = (ks2 & 1) * 2, b1 = b0 + 1;
            unsigned x0 = pk[mkv][b0][0], y0 = pk[mkv][b1][0];
            unsigned x1 = pk[mkv][b0][1], y1 = pk[mkv][b1][1];
            asm volatile("v_permlane32_swap_b32 %0, %1" : "+v"(x0), "+v"(y0));
            asm volatile("v_permlane32_swap_b32 %0, %1" : "+v"(x1), "+v"(y1));
            union { unsigned u[4]; short8 s; } pa;
            pa.u[0] = x0; pa.u[1] = x1; pa.u[2] = y0; pa.u[3] = y1;
            int c = ks2 * 2 + hi;
            #pragma unroll
            for (int ndk = 0; ndk < 2; ++ndk) {
                short8 vf = *reinterpret_cast<const short8*>(
                    &Vs[hf][buf][(c * 64 + ndk * 32 + l31) * 8]);
                o[ndk] = mfma32(pa.s, vf, o[ndk]);
            }
        }
    };

    // ---- main loop: 16 tiles per half, 1-ahead staging ----
    for (int tl = 0; tl < 16; ++tl) {
        if (tl < 15) stage_KV(tl + 1);
        const int buf = tl & 1;

        f32x16 sfr[2] = {};
        __builtin_amdgcn_s_setprio(1);
        do_QK(buf, sfr);
        __builtin_amdgcn_s_setprio(0);
        do_softmax(sfr);
        __builtin_amdgcn_s_setprio(1);
        do_PV(buf);
        __builtin_amdgcn_s_setprio(0);

        if (tl < 15) __syncthreads();
    }

    // ---- combine halves through LDS: O=(oL+oR)/(lL+lR) ----
    __syncthreads();               // all streaming reads/writes done
    float* comb  = reinterpret_cast<float*>(&Ks[0][0][0]);   // 8192 floats
    float* lcomb = reinterpret_cast<float*>(&Vs[0][0][0]);   // 256 floats
    if (hf == 1) {
        #pragma unroll
        for (int ndk = 0; ndk < 2; ++ndk)
            #pragma unroll
            for (int r = 0; r < 16; ++r)
                comb[((wq * 2 + ndk) * 16 + r) * 64 + lane] = o[ndk][r];
        lcomb[wq * 64 + lane] = lsum;
    }
    __syncthreads();
    if (hf == 0) {
        lsum += lcomb[wq * 64 + lane];
        float lfull = lsum + __shfl_xor(lsum, 32, 64);
        float linv = 1.0f / lfull;
        #pragma unroll
        for (int ndk = 0; ndk < 2; ++ndk)
            #pragma unroll
            for (int r = 0; r < 16; ++r)
                o[ndk][r] += comb[((wq * 2 + ndk) * 16 + r) * 64 + lane];
        #pragma unroll
        for (int r = 0; r < 16; ++r) {
            int qloc = (r & 3) + 8 * (r >> 2) + 4 * hi;
            float li = __shfl(linv, qloc, 64);
            int sg = q0 + wq * 32 + qloc;
            #pragma unroll
            for (int ndk = 0; ndk < 2; ++ndk) {
                int dk = ndk * 32 + l31;
                am[((size_t)b * SS + sg) * DM + h * DKH + dk] =
                    f2bf(o[ndk][r] * li);
            }
        }
    }
}

// ---------------------------------------------------------------------------
// Kernel 3: output projection, 64x128 tile (grid 512), BK=32, 2-phase dbuf.
// ---------------------------------------------------------------------------
__global__ __launch_bounds__(256, 4)
void out_proj_kernel(const unsigned short* __restrict__ am,
                     const unsigned short* __restrict__ Wt,
                     const float* __restrict__ bo,
                     float* __restrict__ out)
{
    __shared__ unsigned short As[2][64 * 32];
    __shared__ unsigned short Bs[2][128 * 32];

    const int tid = threadIdx.x, lane = tid & 63, w = tid >> 6;
    const int wm = w & 1, wn = w >> 1;
    const int row16 = lane & 15, kg = lane >> 4;
    const int m0 = blockIdx.x * 64;
    const int n0 = blockIdx.y * 128;

    auto stage = [&](int kt, int buf) {
        {
            int r = tid >> 2, c = tid & 3;
            gl16(&am[(size_t)(m0 + r) * DM + kt * 32 + ((c ^ (r & 3)) * 8)],
                 (char*)As + (size_t)buf * 4096 + (size_t)(w * 64) * 16);
        }
        #pragma unroll
        for (int i = 0; i < 2; ++i) {
            int cc = tid + i * 256;
            int n = cc >> 2, c = cc & 3;
            gl16(&Wt[(size_t)(n0 + n) * DM + kt * 32 + ((c ^ (n & 3)) * 8)],
                 (char*)Bs + (size_t)buf * 8192 + (size_t)(w * 64 + i * 256) * 16);
        }
    };

    f32x4 acc[2][4] = {};

    stage(0, 0);
    vmcnt0();
    __syncthreads();

    for (int t = 0; t < 16; ++t) {
        const int cur = t & 1, nxt = cur ^ 1;
        if (t + 1 < 16) stage(t + 1, nxt);

        short8 af[2], bfr[4];
        #pragma unroll
        for (int i = 0; i < 2; ++i) {
            int ra = wm * 32 + i * 16 + row16;
            af[i] = *reinterpret_cast<const short8*>(
                &As[cur][ra * 32 + ((kg ^ (ra & 3)) * 8)]);
        }
        #pragma unroll
        for (int i = 0; i < 4; ++i) {
            int rb = wn * 64 + i * 16 + row16;
            bfr[i] = *reinterpret_cast<const short8*>(
                &Bs[cur][rb * 32 + ((kg ^ (rb & 3)) * 8)]);
        }
        __builtin_amdgcn_s_setprio(1);
        #pragma unroll
        for (int mf = 0; mf < 2; ++mf)
            #pragma unroll
            for (int nf = 0; nf < 4; ++nf)
                acc[mf][nf] = mfma16(af[mf], bfr[nf], acc[mf][nf]);
        __builtin_amdgcn_s_setprio(0);

        vmcnt0();
        __syncthreads();
    }

    #pragma unroll
    for (int nf = 0; nf < 4; ++nf) {
        int n = n0 + wn * 64 + nf * 16 + row16;
        float bval = bo[n];
        #pragma unroll
        for (int mf = 0; mf < 2; ++mf)
            #pragma unroll
            for (int j = 0; j < 4; ++j) {
                int mrow = m0 + wm * 32 + mf * 16 + kg * 4 + j;
                out[(size_t)mrow * DM + n] = acc[mf][nf][j] + bval;
            }
    }
}

// ---------------------------------------------------------------------------
extern "C" void kernel_launch(void* const* d_in, const int* in_sizes, int n_in,
                              void* d_out, int out_size, void* d_ws, size_t ws_size,
                              hipStream_t stream) {
    const float* Q  = (const float*)d_in[0];
    const float* K  = (const float*)d_in[1];
    const float* V  = (const float*)d_in[2];
    const float* Wq = (const float*)d_in[3];
    const float* bq = (const float*)d_in[4];
    const float* Wk = (const float*)d_in[5];
    const float* bk = (const float*)d_in[6];
    const float* Wv = (const float*)d_in[7];
    const float* bv = (const float*)d_in[8];
    const float* Wo = (const float*)d_in[9];
    const float* bo = (const float*)d_in[10];
    float* out = (float*)d_out;

    const size_t per = (size_t)BB * NH * SS * DKH;   // 4,194,304 bf16 elems
    unsigned short* qb  = (unsigned short*)d_ws;     // [bh][s][dk]
    unsigned short* kb2 = qb + per;                  // tiled K
    unsigned short* vt2 = kb2 + per;                 // tiled V^T
    unsigned short* am  = vt2 + per;
    unsigned short* wt  = am + per;                  // 4 x 512x512 bf16

    prep_w<<<dim3(8, 8, 4), 256, 0, stream>>>(Wq, Wk, Wv, Wo, wt);
    qkv_proj_kernel<<<dim3(64, 4, 3), 256, 0, stream>>>(
        Q, K, V, wt, bq, bk, bv, qb, kb2, vt2);
    attn_kernel<<<dim3(SS / 128, BB * NH), 512, 0, stream>>>(qb, kb2, vt2, am);
    out_proj_kernel<<<dim3(128, 4), 256, 0, stream>>>(
        am, wt + 3 * (size_t)DM * DM, bo, out);
}